// Round 8
// baseline (118734.546 us; speedup 1.0000x reference)
//
#include <hip/hip_runtime.h>
#include <math.h>

typedef unsigned long long ull;
typedef unsigned int u32;

#define Bsz 64
#define Tt  1024
#define TH  512      // entities/slices < T/2, lens >= T/2 -> enc only needed for t < 512

// LDS float offsets
#define BUF0 0
#define BUF1 8192
#define QLDS 16384
#define RLDS 20480
#define PART 24576          // [8][16][33] = 4224
#define SMEMF 28800         // floats (115200 B)

__device__ __forceinline__ float sigm(float x){ return 1.f/(1.f+expf(-x)); }
__device__ __forceinline__ float fma4(float4 w, float4 x, float a){
  return fmaf(w.x,x.x,fmaf(w.y,x.y,fmaf(w.z,x.z,fmaf(w.w,x.w,a))));
}

// Qp[d][j][k] = Q[d][k][j]; Rp likewise (transpose to col-major-by-output).
__global__ void pack_k(const float* __restrict__ Q, const float* __restrict__ R,
                       float* __restrict__ Qp, float* __restrict__ Rp){
  int idx = blockIdx.x*256 + threadIdx.x;
  if (idx >= 131072) return;
  int d = idx>>16, r = idx&65535, j = r>>8, k = r&255;
  Qp[idx] = Q[d*65536 + k*256 + j];
  Rp[idx] = R[d*65536 + k*256 + j];
}

// 64 WGs = 2 dirs x 2 clusters(32 batches) x 16 col-slices. Per WG: Q/R col-slices
// stationary in LDS; GRU rows streamed from L2; activation exchange via tagged-u64
// relaxed agent atomics (tag = step+1 packed with the fp32 value in one atom).
__global__ __launch_bounds__(512) void scan_k(
    const int* __restrict__ sents, const int* __restrict__ lens,
    const float* __restrict__ emb,
    const float* __restrict__ Qp, const float* __restrict__ Rp,
    const float* __restrict__ Wih_f, const float* __restrict__ Whh_f,
    const float* __restrict__ Wih_b, const float* __restrict__ Whh_b,
    const float* __restrict__ bih_f, const float* __restrict__ bhh_f,
    const float* __restrict__ bih_b, const float* __restrict__ bhh_b,
    ull* __restrict__ pub, float* __restrict__ enc)
{
  extern __shared__ float sm[];
  const int bx  = blockIdx.x;               // 0..63
  const int xcd = bx & 7;
  const int dir = xcd >> 2;                 // XCD-grouped for weight L2 locality
  const int id  = (xcd & 3) + 4*(bx>>3);    // 0..31 within dir
  const int cl  = id >> 4, wgi = id & 15;
  const int cid = dir*2 + cl;
  const int bbase = cl*32;

  const int tid = threadIdx.x;
  const int wv = tid>>6, ln = tid&63;
  const int b = ln & 31, half = ln>>5;
  const int cloc = 2*wv + half;             // 0..15 (same map every phase)
  const int colg = wgi*16 + cloc;
  const int gb = bbase + b;

  const float* Qd  = Qp + dir*65536;
  const float* Rd  = Rp + dir*65536;
  const float* Wih = dir ? Wih_b : Wih_f;
  const float* Whh = dir ? Whh_b : Whh_f;
  const float* bih = dir ? bih_b : bih_f;
  const float* bhh = dir ? bhh_b : bhh_f;

  for (int i = tid; i < 4096; i += 512){    // stationary Q/R col-slices -> LDS
    int c = i>>8, k = i&255;
    sm[QLDS + i] = Qd[(wgi*16+c)*256 + k];
    sm[RLDS + i] = Rd[(wgi*16+c)*256 + k];
  }

  ull* pubP = pub + (size_t)cid*5*8192;
  ull* pA = pubP;            ull* pB = pubP+8192;  ull* pC = pubP+16384;
  ull* pD = pubP+24576;      ull* pE = pubP+32768;

  const float bi_r = bih[colg], bi_z = bih[colg+256], bi_n = bih[colg+512];
  const float bh_r = bhh[colg], bh_z = bhh[colg+256], bh_n = bhh[colg+512];
  const float4* WIr = (const float4*)(Wih + (size_t)colg*256);
  const float4* WIz = (const float4*)(Wih + (size_t)(colg+256)*256);
  const float4* WIn = (const float4*)(Wih + (size_t)(colg+512)*256);
  const float4* WHr = (const float4*)(Whh + (size_t)colg*256);
  const float4* WHz = (const float4*)(Whh + (size_t)(colg+256)*256);
  const float4* WHn = (const float4*)(Whh + (size_t)(colg+512)*256);

  const int mylen = lens[gb];
  int nsteps = 0;
  if (!dir) nsteps = TH;                    // fwd: only t<512 observable
  else { for (int i=0;i<32;++i) nsteps = max(nsteps, lens[bbase+i]); }
  int t = dir ? (nsteps-1) : 0;
  const int tstep = dir ? -1 : 1;

  int ck4[4], cb[4];                        // gather cells: 4 per thread
  #pragma unroll
  for (int i=0;i<4;++i){ int c = i*512+tid; ck4[i]=c>>5; cb[i]=c&31; }

  auto gather = [&](const ull* __restrict__ p, int bufoff, u32 tg){
    ull v[16];
    #pragma unroll
    for (int i=0;i<4;++i)
      #pragma unroll
      for (int kk=0;kk<4;++kk)
        v[i*4+kk] = __hip_atomic_load(p + (size_t)(ck4[i]*4+kk)*32 + cb[i],
                      __ATOMIC_RELAXED, __HIP_MEMORY_SCOPE_AGENT);
    for (;;){
      bool bad = false;
      #pragma unroll
      for (int i=0;i<4;++i)
        #pragma unroll
        for (int kk=0;kk<4;++kk){
          int j = i*4+kk;
          if ((u32)(v[j]>>32) != tg){
            v[j] = __hip_atomic_load(p + (size_t)(ck4[i]*4+kk)*32 + cb[i],
                      __ATOMIC_RELAXED, __HIP_MEMORY_SCOPE_AGENT);
            if ((u32)(v[j]>>32) != tg) bad = true;
          }
        }
      if (!bad) break;
    }
    #pragma unroll
    for (int i=0;i<4;++i){
      float4 f = make_float4(__uint_as_float((u32)v[i*4+0]), __uint_as_float((u32)v[i*4+1]),
                             __uint_as_float((u32)v[i*4+2]), __uint_as_float((u32)v[i*4+3]));
      *(float4*)&sm[bufoff + (ck4[i]*32+cb[i])*4] = f;
    }
  };

  // k-split (per wave) mog matvec + LDS reduce + tagged publish. Returns own value.
  auto mogphase = [&](int woff, int inoff, ull* pdst, float mul, u32 tg)->float{
    float acc[8];
    #pragma unroll
    for (int r=0;r<8;++r) acc[r]=0.f;
    const int k4b = wv*8;
    #pragma unroll
    for (int i=0;i<8;++i){
      int k4 = k4b+i;
      float4 x = *(const float4*)&sm[inoff + (k4*32+b)*4];
      #pragma unroll
      for (int r=0;r<8;++r){
        float4 w = *(const float4*)&sm[woff + ((half*8+r)*256 + k4*4)];
        acc[r] = fma4(w,x,acc[r]);
      }
    }
    #pragma unroll
    for (int r=0;r<8;++r)
      sm[PART + (wv*16 + half*8+r)*33 + b] = acc[r];
    __syncthreads();
    float s0 = 0.f;
    #pragma unroll
    for (int p2=0;p2<8;++p2) s0 += sm[PART + (p2*16 + cloc)*33 + b];
    float val = 2.f*sigm(s0)*mul;
    ull u = ((ull)tg<<32) | (ull)__float_as_uint(val);
    __hip_atomic_store(pdst + (size_t)colg*32 + b, u,
                       __ATOMIC_RELAXED, __HIP_MEMORY_SCOPE_AGENT);
    return val;
  };

  __syncthreads();

  for (int s=0; s<nsteps; ++s, t+=tstep){
    const u32 tg = (u32)(s+1);
    int tok = sents[gb*Tt + t];
    float x0 = emb[(size_t)tok*256 + colg];

    if (s==0){
      #pragma unroll
      for (int i=0;i<4;++i)
        *(float4*)&sm[BUF0 + (ck4[i]*32+cb[i])*4] = make_float4(0.f,0.f,0.f,0.f);
    } else gather(pE, BUF0, (u32)s);        // h(s-1) tagged s
    __syncthreads();
    float hprev = sm[BUF0 + ((colg>>2)*32+b)*4 + (colg&3)];

    float x1  = mogphase(QLDS, BUF0, pA, x0, tg);     // A: x1 = 2sig(h@Q)*x0
    gather(pA, BUF1, tg);  __syncthreads();
    float hm1 = mogphase(RLDS, BUF1, pB, hprev, tg);  // B: hm1 = 2sig(x1@R)*h
    gather(pB, BUF0, tg);  __syncthreads();
    float x2  = mogphase(QLDS, BUF0, pC, x1, tg);     // C: x2 = 2sig(hm1@Q)*x1
    gather(pC, BUF1, tg);  __syncthreads();
    float hm2 = mogphase(RLDS, BUF1, pD, hm1, tg);    // D: hm2 = 2sig(x2@R)*hm1
    gather(pD, BUF0, tg);  __syncthreads();

    // E: GRU — xi = x2 (BUF1), xh = hm2 (BUF0); 6 dots, weights from L2.
    float gr=0,gz=0,gn=0,hr=0,hz=0,hn=0;
    #pragma unroll 2
    for (int k4=0;k4<64;++k4){
      float4 xi = *(const float4*)&sm[BUF1 + (k4*32+b)*4];
      float4 xh = *(const float4*)&sm[BUF0 + (k4*32+b)*4];
      gr = fma4(WIr[k4], xi, gr);
      gz = fma4(WIz[k4], xi, gz);
      gn = fma4(WIn[k4], xi, gn);
      hr = fma4(WHr[k4], xh, hr);
      hz = fma4(WHz[k4], xh, hz);
      hn = fma4(WHn[k4], xh, hn);
    }
    float r = sigm(gr+bi_r+hr+bh_r);
    float z = sigm(gz+bi_z+hz+bh_z);
    float n = tanhf(gn+bi_n + r*(hn+bh_n));
    float uu = (1.f-z)*n + z*hm2;
    bool m = (t < mylen);
    float hnew = m ? uu : hprev;
    ull e = ((ull)tg<<32) | (ull)__float_as_uint(hnew);
    __hip_atomic_store(pE + (size_t)colg*32 + b, e,
                       __ATOMIC_RELAXED, __HIP_MEMORY_SCOPE_AGENT);
    if (m && t < TH)
      atomicAdd(&enc[((size_t)gb*TH + t)*256 + colg], uu);
    __syncthreads();    // protect BUF re-stage next step vs E readers
  }
}

// One WG per batch element. Reproduces gate_attention + attention + dense exactly.
__global__ __launch_bounds__(256) void epi_k(
    const float* __restrict__ enc,
    const int* __restrict__ entities, const int* __restrict__ slices,
    const float* __restrict__ slice_lens,
    const int* __restrict__ entity_masks, const int* __restrict__ slice_masks,
    const float* __restrict__ ent_W, const float* __restrict__ ent_b,
    const float* __restrict__ att_w,
    const float* __restrict__ dense_W, const float* __restrict__ dense_b,
    float* __restrict__ out)
{
    const int b = blockIdx.x;
    const int j = threadIdx.x;
    const int wave = j >> 6, lane = j & 63;

    __shared__ float ee[8][256];
    __shared__ float p[256];
    __shared__ float rela[256];
    __shared__ float sc[264];
    __shared__ float red[4];
    __shared__ float aw[256];
    __shared__ int   spos[256];

    aw[j]   = att_w[j];
    spos[j] = slices[b * 256 + j];
    #pragma unroll
    for (int e = 0; e < 8; ++e)
        ee[e][j] = enc[((size_t)b * TH + entities[b * 8 + e]) * 256 + j];
    __syncthreads();

    float entWj = ent_W[j];
    for (int e = 0; e < 8; ++e) {
        float v = ee[e][j] * entWj;
        #pragma unroll
        for (int o = 32; o > 0; o >>= 1) v += __shfl_down(v, o);
        if (lane == 0) red[wave] = v;
        __syncthreads();
        if (j == 0) sc[e] = red[0] + red[1] + red[2] + red[3] + ent_b[0];
        __syncthreads();
    }
    float mx = -INFINITY;
    float ewv[8];
    #pragma unroll
    for (int e = 0; e < 8; ++e) {
        float v = entity_masks[b * 8 + e] ? sc[e] : -INFINITY;
        ewv[e] = v; mx = fmaxf(mx, v);
    }
    float den = 0.f;
    #pragma unroll
    for (int e = 0; e < 8; ++e) {
        ewv[e] = entity_masks[b * 8 + e] ? expf(ewv[e] - mx) : 0.f;
        den += ewv[e];
    }
    float accp = 0.f;
    #pragma unroll
    for (int e = 0; e < 8; ++e) accp += (ewv[e] / den) * ee[e][j];
    p[j] = tanhf(accp);
    __syncthreads();

    for (int s0 = wave; s0 < 256; s0 += 4) {
        const float* row = enc + ((size_t)b * TH + spos[s0]) * 256;
        float v = 0.f;
        #pragma unroll
        for (int i = 0; i < 4; ++i) { int c = lane + 64 * i; v += row[c] * p[c]; }
        #pragma unroll
        for (int o = 32; o > 0; o >>= 1) v += __shfl_down(v, o);
        if (lane == 0) sc[s0] = v;
    }
    __syncthreads();

    float sl  = slice_lens[b];
    int   smk = slice_masks[b * 256 + j];
    float wv  = smk ? sc[j] : -INFINITY;
    float bm = wv;
    #pragma unroll
    for (int o = 32; o > 0; o >>= 1) bm = fmaxf(bm, __shfl_down(bm, o));
    __syncthreads();
    if (lane == 0) red[wave] = bm;
    __syncthreads();
    bm = fmaxf(fmaxf(red[0], red[1]), fmaxf(red[2], red[3]));
    float ex = smk ? expf(wv - bm) : 0.f;
    float sm2 = ex;
    #pragma unroll
    for (int o = 32; o > 0; o >>= 1) sm2 += __shfl_down(sm2, o);
    __syncthreads();
    if (lane == 0) red[wave] = sm2;
    __syncthreads();
    sm2 = red[0] + red[1] + red[2] + red[3];
    float ww = ex / sm2 * sl;
    float rl = (ww > 0.05f) ? (ww / sl) : 0.f;   // BETA = 0.05
    float rm = rl;
    #pragma unroll
    for (int o = 32; o > 0; o >>= 1) rm = fmaxf(rm, __shfl_down(rm, o));
    __syncthreads();
    if (lane == 0) red[wave] = rm;
    __syncthreads();
    rm = fmaxf(fmaxf(red[0], red[1]), fmaxf(red[2], red[3]));
    rl = rl / rm;
    rela[j] = rl;
    __syncthreads();

    for (int n = wave; n < 264; n += 4) {
        float v = 0.f;
        if (n < 8) {
            #pragma unroll
            for (int i = 0; i < 4; ++i) { int c = lane + 64 * i; v += tanhf(ee[n][c]) * aw[c]; }
        } else {
            int s0 = n - 8;
            const float* row = enc + ((size_t)b * TH + spos[s0]) * 256;
            float rl2 = rela[s0];
            #pragma unroll
            for (int i = 0; i < 4; ++i) { int c = lane + 64 * i; v += tanhf(rl2 * row[c]) * aw[c]; }
        }
        #pragma unroll
        for (int o = 32; o > 0; o >>= 1) v += __shfl_down(v, o);
        if (lane == 0) sc[n] = v;
    }
    __syncthreads();

    float a1 = sc[j];       a1 = (a1 == 0.f) ? -INFINITY : a1;
    float a2 = (j < 8) ? sc[256 + j] : -INFINITY;
    if (a2 == 0.f) a2 = -INFINITY;
    float am = fmaxf(a1, a2);
    #pragma unroll
    for (int o = 32; o > 0; o >>= 1) am = fmaxf(am, __shfl_down(am, o));
    __syncthreads();
    if (lane == 0) red[wave] = am;
    __syncthreads();
    am = fmaxf(fmaxf(red[0], red[1]), fmaxf(red[2], red[3]));
    float e1 = (a1 == -INFINITY) ? 0.f : expf(a1 - am);
    float e2 = (a2 == -INFINITY) ? 0.f : expf(a2 - am);
    float esum = e1 + e2;
    #pragma unroll
    for (int o = 32; o > 0; o >>= 1) esum += __shfl_down(esum, o);
    __syncthreads();
    if (lane == 0) red[wave] = esum;
    __syncthreads();
    esum = red[0] + red[1] + red[2] + red[3];
    __syncthreads();
    sc[j] = e1 / esum;
    if (j < 8) sc[256 + j] = e2 / esum;
    __syncthreads();

    float att = 0.f;
    #pragma unroll
    for (int n = 0; n < 8; ++n) att += sc[n] * ee[n][j];
    for (int s0 = 0; s0 < 256; ++s0) {
        float scn = sc[8 + s0];
        if (scn > 0.f)
            att += scn * rela[s0] * enc[((size_t)b * TH + spos[s0]) * 256 + j];
    }
    float ta = tanhf(att);

    for (int l = 0; l < 19; ++l) {
        float v = ta * dense_W[l * 256 + j];
        #pragma unroll
        for (int o = 32; o > 0; o >>= 1) v += __shfl_down(v, o);
        __syncthreads();
        if (lane == 0) red[wave] = v;
        __syncthreads();
        if (j == 0) out[b * 19 + l] = red[0] + red[1] + red[2] + red[3] + dense_b[l];
    }
}

extern "C" void kernel_launch(void* const* d_in, const int* in_sizes, int n_in,
                              void* d_out, int out_size, void* d_ws, size_t ws_size,
                              hipStream_t stream) {
    (void)in_sizes; (void)n_in; (void)out_size; (void)ws_size;
    const int*   sents        = (const int*)d_in[0];
    const int*   lens         = (const int*)d_in[1];
    const int*   entities     = (const int*)d_in[2];
    const int*   slices       = (const int*)d_in[3];
    const float* slice_lens   = (const float*)d_in[4];
    const int*   entity_masks = (const int*)d_in[5];
    const int*   slice_masks  = (const int*)d_in[6];
    const float* emb          = (const float*)d_in[7];
    const float* Q            = (const float*)d_in[8];
    const float* R            = (const float*)d_in[9];
    const float* Wih_f        = (const float*)d_in[10];
    const float* Whh_f        = (const float*)d_in[11];
    const float* bih_f        = (const float*)d_in[12];
    const float* bhh_f        = (const float*)d_in[13];
    const float* Wih_b        = (const float*)d_in[14];
    const float* Whh_b        = (const float*)d_in[15];
    const float* bih_b        = (const float*)d_in[16];
    const float* bhh_b        = (const float*)d_in[17];
    const float* ent_W        = (const float*)d_in[18];
    const float* ent_b        = (const float*)d_in[19];
    const float* att_w        = (const float*)d_in[20];
    const float* dense_W      = (const float*)d_in[21];
    const float* dense_b      = (const float*)d_in[22];

    // ws: enc [64][512][256] f32 (33.5MB) | Qp 131072 f | Rp 131072 f | pub 163840 u64
    float* enc = (float*)d_ws;
    float* Qp  = enc + (size_t)Bsz * TH * 256;
    float* Rp  = Qp + 131072;
    ull*   pub = (ull*)(Rp + 131072);

    const int smem_bytes = SMEMF * 4;   // 115200 B
    hipFuncSetAttribute(reinterpret_cast<const void*>(scan_k),
                        hipFuncAttributeMaxDynamicSharedMemorySize, smem_bytes);

    hipMemsetAsync(enc, 0, (size_t)Bsz * TH * 256 * sizeof(float), stream);
    hipMemsetAsync(pub, 0, (size_t)4 * 5 * 8192 * sizeof(ull), stream);
    pack_k<<<512, 256, 0, stream>>>(Q, R, Qp, Rp);
    scan_k<<<64, 512, smem_bytes, stream>>>(sents, lens, emb, Qp, Rp,
                                            Wih_f, Whh_f, Wih_b, Whh_b,
                                            bih_f, bhh_f, bih_b, bhh_b,
                                            pub, enc);
    epi_k<<<64, 256, 0, stream>>>(enc, entities, slices, slice_lens,
                                  entity_masks, slice_masks, ent_W, ent_b,
                                  att_w, dense_W, dense_b, (float*)d_out);
}

// Round 9
// 19479.239 us; speedup vs baseline: 6.0954x; 6.0954x over previous
//
#include <hip/hip_runtime.h>
#include <hip/hip_fp16.h>
#include <math.h>

typedef unsigned int uint;

#define Bsz 64
#define Tt  1024
#define TH  512      // entities/slices < T/2, lens >= T/2 -> enc only needed for t < 512

// LDS float offsets
#define XSF   768    // float[512]  x acts (f32, for GRU)
#define HMF   1280   // float[512]  hm acts (f32, for GRU)
#define PARTF 1792   // 12288 floats (mog 8x512 / gru 8x1536 overlay)
#define DMAF  14080  // 8 waves x 3 slots x 1024 floats
#define SMEMF 38656  // 154624 B
// half offsets (into smH): xs_h 0..512, hcs_h 512..1024, hms_h 1024..1536

typedef _Float16 h2 __attribute__((ext_vector_type(2)));

#if defined(__has_builtin)
#if __has_builtin(__builtin_amdgcn_fdot2)
#define HAS_FDOT2 1
#endif
#endif

__device__ __forceinline__ float sigm(float x){ return 1.f/(1.f+expf(-x)); }

#define GLOAD16(g,l) __builtin_amdgcn_global_load_lds( \
    (const __attribute__((address_space(1))) void*)(g), \
    (__attribute__((address_space(3))) void*)(l), 16, 0, 0)
#define VM8 asm volatile("s_waitcnt vmcnt(8)":::"memory")
#define VM4 asm volatile("s_waitcnt vmcnt(4)":::"memory")
#define VM0 asm volatile("s_waitcnt vmcnt(0)":::"memory")
#define LG0 asm volatile("s_waitcnt lgkmcnt(0)":::"memory")
#define BAR __builtin_amdgcn_s_barrier

// (w_k0,w_k1) fp16 pair dotted against 2 batches' fp16 act pairs, f32 accum.
__device__ __forceinline__ void dot2b(uint w, uint a0, uint a1, float& s0, float& s1){
  h2 wh = __builtin_bit_cast(h2, w);
#ifdef HAS_FDOT2
  s0 = __builtin_amdgcn_fdot2(wh, __builtin_bit_cast(h2, a0), s0, false);
  s1 = __builtin_amdgcn_fdot2(wh, __builtin_bit_cast(h2, a1), s1, false);
#else
  h2 x0 = __builtin_bit_cast(h2, a0), x1 = __builtin_bit_cast(h2, a1);
  s0 = fmaf((float)wh.x,(float)x0.x, fmaf((float)wh.y,(float)x0.y, s0));
  s1 = fmaf((float)wh.x,(float)x1.x, fmaf((float)wh.y,(float)x1.y, s1));
#endif
}

// Pack all weights to fp16 in per-(dir,wave) consumption-ordered 4KB units.
// Stream layout (halfs): QH [0,131072) | RH [131072,262144) | GH [262144,1048576).
// Q/R unit u (of 4, wave w): cols c<256, halfs jj<8 = W[32w+8u+jj][c].
// G unit e = u8*3+g (of 24, wave w: mat=w&1, ks=w>>1): W[g*256+c][64ks+8u8+jj].
__global__ void pack_k(const float* __restrict__ Q, const float* __restrict__ R,
                       const float* __restrict__ Wih_f, const float* __restrict__ Whh_f,
                       const float* __restrict__ Wih_b, const float* __restrict__ Whh_b,
                       __half* __restrict__ Wh)
{
  int ci = blockIdx.x*256 + threadIdx.x;       // 16B cell index, 131072 total
  if (ci >= 131072) return;
  float v[8];
  if (ci < 32768){
    bool isR = ci >= 16384;
    int c0 = ci & 16383;
    int c = c0 & 255;
    int rest = c0 >> 8;                        // (d*8+w)*4+u
    int u = rest & 3, dw = rest >> 2;
    int w = dw & 7, d = dw >> 3;
    const float* S = (isR ? R : Q) + d*65536;  // [k][j]
    int k0 = 32*w + 8*u;
    #pragma unroll
    for (int j=0;j<8;++j) v[j] = S[(k0+j)*256 + c];
  } else {
    int c0 = ci - 32768;                       // 98304 cells
    int c = c0 & 255;
    int rest = c0 >> 8;                        // (d*8+w)*24+e
    int e = rest % 24, dw = rest / 24;
    int w = dw & 7, d = dw >> 3;
    int mat = w & 1, ks = w >> 1;
    int u8 = e / 3, g = e % 3;
    const float* W = mat ? (d? Whh_b : Whh_f) : (d? Wih_b : Wih_f);  // [768][256]
    const float* row = W + (size_t)(g*256 + c)*256 + (64*ks + 8*u8);
    #pragma unroll
    for (int j=0;j<8;++j) v[j] = row[j];
  }
  __half h8[8];
  #pragma unroll
  for (int j=0;j<8;++j) h8[j] = __float2half(v[j]);
  *(uint4*)(Wh + (size_t)ci*8) = *(uint4*)h8;
}

// One WG of 512 threads per (direction, batch-pair), dir grouped per XCD.
// fp16 weights stream via per-wave 3-slot global_load_lds ring, counted vmcnt.
// Carry chain (h, x1, hm1, hm2) stays f32 in registers; no __syncthreads in loop.
__global__ __launch_bounds__(512) void scan_k(
    const int* __restrict__ sents, const int* __restrict__ lens,
    const float* __restrict__ emb,
    const float* __restrict__ bih_f, const float* __restrict__ bhh_f,
    const float* __restrict__ bih_b, const float* __restrict__ bhh_b,
    const __half* __restrict__ Wh, float* __restrict__ enc)
{
  extern __shared__ float sm[];
  __half* smH = (__half*)sm;

  const int bx = blockIdx.x;                 // 0..63
  const int dir  = ((bx & 7) >= 4) ? 1 : 0;  // dir constant per XCD residue class
  const int pair = (bx >> 3)*4 + (bx & 3);   // 0..31
  const int b0 = pair*2;
  const int tid = threadIdx.x;
  const int wv = tid >> 6, ln = tid & 63;
  const int cj = tid & 255, cb = tid >> 8;   // finalize (col, batch)
  const int matE = wv & 1, ksE = wv >> 1;    // GRU wave roles

  const __half* QB = Wh + (size_t)((dir*8+wv)*4)*2048;
  const __half* RB = Wh + 131072 + (size_t)((dir*8+wv)*4)*2048;
  const __half* GB = Wh + 262144 + (size_t)((dir*8+wv)*24)*2048;
  const float* bih = dir ? bih_b : bih_f;
  const float* bhh = dir ? bhh_b : bhh_f;

  const int len0 = lens[b0], len1 = lens[b0+1];
  const int mylen = cb ? len1 : len0;
  const float bi_r = bih[cj], bi_z = bih[cj+256], bi_n = bih[cj+512];
  const float bh_r = bhh[cj], bh_z = bhh[cj+256], bh_n = bhh[cj+512];

  int nsteps, t, tstep;
  if (!dir){ nsteps = TH; t = 0; tstep = 1; }                       // fwd: t<512 observable
  else { int mx = max(len0,len1); nsteps = mx; t = mx-1; tstep = -1; } // bwd: h==0 while masked

  smH[512 + tid] = (__half)0.f;              // hcs_h zero

  auto uaddr = [&](int u)->const __half*{
    if (u < 16){ const __half* B = (u & 4) ? RB : QB; return B + (u & 3)*2048; }
    return GB + (u - 16)*2048;
  };
  char* dmabase = (char*)(sm + DMAF + wv*3072);
  int rslot = 0, nextu = 3;
  auto ISSUE = [&](int u, int slot){
    const char* gp = (const char*)uaddr(u) + ln*16;
    char* lp = dmabase + slot*4096;
    GLOAD16(gp,        lp);
    GLOAD16(gp + 1024, lp + 1024);
    GLOAD16(gp + 2048, lp + 2048);
    GLOAD16(gp + 3072, lp + 3072);
  };
  ISSUE(0,0); ISSUE(1,1); ISSUE(2,2);

  // k-split mog partials: 4 units, dot2 vs fp16 acts at half-offset actsHO.
  auto mog_part = [&](int actsHO){
    float2 acc[4];
    acc[0]=acc[1]=acc[2]=acc[3]=make_float2(0.f,0.f);
    #pragma unroll
    for (int u=0; u<4; ++u){
      const int k8 = 4*wv + u;
      const uint4 a0 = *(const uint4*)(smH + actsHO +       k8*8);
      const uint4 a1 = *(const uint4*)(smH + actsHO + 256 + k8*8);
      VM8;
      const char* wb = dmabase + rslot*4096;
      uint4 W0 = *(const uint4*)(wb +  ln      *16);
      uint4 W1 = *(const uint4*)(wb + (ln+ 64) *16);
      uint4 W2 = *(const uint4*)(wb + (ln+128) *16);
      uint4 W3 = *(const uint4*)(wb + (ln+192) *16);
      LG0;
      ISSUE(nextu, rslot);
      if (++rslot == 3) rslot = 0;
      if (++nextu == 40) nextu = 0;
      const uint* A0=(const uint*)&a0; const uint* A1=(const uint*)&a1;
      const uint* w0=(const uint*)&W0; const uint* w1=(const uint*)&W1;
      const uint* w2=(const uint*)&W2; const uint* w3=(const uint*)&W3;
      #pragma unroll
      for (int i=0;i<4;++i){
        dot2b(w0[i],A0[i],A1[i],acc[0].x,acc[0].y);
        dot2b(w1[i],A0[i],A1[i],acc[1].x,acc[1].y);
        dot2b(w2[i],A0[i],A1[i],acc[2].x,acc[2].y);
        dot2b(w3[i],A0[i],A1[i],acc[3].x,acc[3].y);
      }
    }
    #pragma unroll
    for (int q=0;q<4;++q)
      *(float2*)(sm + PARTF + wv*512 + (ln+64*q)*2) = acc[q];
  };
  // finalize mog: sum 8 partials, gate, write half (+optional f32) act copy.
  auto mog_fin = [&](float mult, int dstHO, int dstFO)->float{
    float ssum = 0.f;
    #pragma unroll
    for (int p=0;p<8;++p) ssum += sm[PARTF + p*512 + cj*2 + cb];
    float val = 2.f*sigm(ssum)*mult;
    smH[dstHO + cb*256 + cj] = (__half)val;
    if (dstFO >= 0) sm[dstFO + cb*256 + cj] = val;
    return val;
  };

  float hprev = 0.f, x1 = 0.f, hm1 = 0.f, hm2 = 0.f;
  LG0; BAR();

  for (int s=0; s<nsteps; ++s, t+=tstep){
    const bool lastst = (s == nsteps-1);
    int tok = sents[(b0+cb)*Tt + t];
    float x0 = emb[(size_t)tok*256 + cj];

    // A: x1 = 2sig(h@Q)*x0
    mog_part(512);                 LG0; BAR();
    x1 = mog_fin(x0, 0, -1);       LG0; BAR();
    // B: hm1 = 2sig(x1@R)*h
    mog_part(0);                   LG0; BAR();
    hm1 = mog_fin(hprev, 1024, -1); LG0; BAR();
    // C: x2 = 2sig(hm1@Q)*x1
    mog_part(1024);                LG0; BAR();
    x1 = mog_fin(x1, 0, XSF);      LG0; BAR();   // x1 now holds x2
    // D: hm2 = 2sig(x2@R)*hm1
    mog_part(0);                   LG0; BAR();
    hm2 = mog_fin(hm1, 1024, HMF); LG0; BAR();

    // E: GRU — gi = x2@Wih^T (mat0 waves), gh = hm2@Whh^T (mat1 waves); f32 acts.
    {
      float2 ag[12];
      #pragma unroll
      for (int i=0;i<12;++i) ag[i] = make_float2(0.f,0.f);
      const int AF = matE ? HMF : XSF;
      for (int u8=0; u8<8; ++u8){
        const int kb = 64*ksE + 8*u8;
        float xf0[8], xf1[8];
        *(float4*)&xf0[0] = *(const float4*)(sm + AF +       kb);
        *(float4*)&xf0[4] = *(const float4*)(sm + AF +       kb + 4);
        *(float4*)&xf1[0] = *(const float4*)(sm + AF + 256 + kb);
        *(float4*)&xf1[4] = *(const float4*)(sm + AF + 256 + kb + 4);
        for (int g=0; g<3; ++g){
          const int c = 16 + u8*3 + g;
          if (__builtin_expect(lastst && c >= 38, 0)) { if (c == 38) VM4; else VM0; }
          else VM8;
          const char* wb = dmabase + rslot*4096;
          uint4 W0 = *(const uint4*)(wb +  ln      *16);
          uint4 W1 = *(const uint4*)(wb + (ln+ 64) *16);
          uint4 W2 = *(const uint4*)(wb + (ln+128) *16);
          uint4 W3 = *(const uint4*)(wb + (ln+192) *16);
          LG0;
          if (!(lastst && c >= 37)) ISSUE(nextu, rslot);
          if (++rslot == 3) rslot = 0;
          if (++nextu == 40) nextu = 0;
          const uint4 WW[4] = {W0,W1,W2,W3};
          #pragma unroll
          for (int q=0;q<4;++q){
            const uint* wq = (const uint*)&WW[q];
            #pragma unroll
            for (int i=0;i<4;++i){
              h2 wh = __builtin_bit_cast(h2, wq[i]);
              float wlo = (float)wh.x, whi = (float)wh.y;
              ag[g*4+q].x = fmaf(wlo, xf0[2*i], fmaf(whi, xf0[2*i+1], ag[g*4+q].x));
              ag[g*4+q].y = fmaf(wlo, xf1[2*i], fmaf(whi, xf1[2*i+1], ag[g*4+q].y));
            }
          }
        }
      }
      #pragma unroll
      for (int g=0;g<3;++g)
        #pragma unroll
        for (int q=0;q<4;++q)
          *(float2*)(sm + PARTF + wv*1536 + (g*256 + ln + 64*q)*2) = ag[g*4+q];
    }
    LG0; BAR();
    {
      float gi[3], gh[3];
      #pragma unroll
      for (int g=0; g<3; ++g){
        float si = 0.f, sh = 0.f;
        #pragma unroll
        for (int p=0;p<4;++p){
          si += sm[PARTF + (p*2+0)*1536 + (g*256+cj)*2 + cb];
          sh += sm[PARTF + (p*2+1)*1536 + (g*256+cj)*2 + cb];
        }
        gi[g] = si; gh[g] = sh;
      }
      float r = sigm(gi[0]+bi_r + gh[0]+bh_r);
      float z = sigm(gi[1]+bi_z + gh[1]+bh_z);
      float n = tanhf(gi[2]+bi_n + r*(gh[2]+bh_n));
      float uu = (1.f - z)*n + z*hm2;
      bool m = (t < mylen);
      float hnew = m ? uu : hprev;
      hprev = hnew;
      smH[512 + cb*256 + cj] = (__half)hnew;
      if (m && t < TH)
        atomicAdd(&enc[((size_t)(b0+cb)*TH + t)*256 + cj], uu);
    }
    LG0; BAR();
  }
}

// One WG per batch element. Reproduces gate_attention + attention + dense exactly.
__global__ __launch_bounds__(256) void epi_k(
    const float* __restrict__ enc,
    const int* __restrict__ entities, const int* __restrict__ slices,
    const float* __restrict__ slice_lens,
    const int* __restrict__ entity_masks, const int* __restrict__ slice_masks,
    const float* __restrict__ ent_W, const float* __restrict__ ent_b,
    const float* __restrict__ att_w,
    const float* __restrict__ dense_W, const float* __restrict__ dense_b,
    float* __restrict__ out)
{
    const int b = blockIdx.x;
    const int j = threadIdx.x;
    const int wave = j >> 6, lane = j & 63;

    __shared__ float ee[8][256];
    __shared__ float p[256];
    __shared__ float rela[256];
    __shared__ float sc[264];
    __shared__ float red[4];
    __shared__ float aw[256];
    __shared__ int   spos[256];

    aw[j]   = att_w[j];
    spos[j] = slices[b * 256 + j];
    #pragma unroll
    for (int e = 0; e < 8; ++e)
        ee[e][j] = enc[((size_t)b * TH + entities[b * 8 + e]) * 256 + j];
    __syncthreads();

    float entWj = ent_W[j];
    for (int e = 0; e < 8; ++e) {
        float v = ee[e][j] * entWj;
        #pragma unroll
        for (int o = 32; o > 0; o >>= 1) v += __shfl_down(v, o);
        if (lane == 0) red[wave] = v;
        __syncthreads();
        if (j == 0) sc[e] = red[0] + red[1] + red[2] + red[3] + ent_b[0];
        __syncthreads();
    }
    float mx = -INFINITY;
    float ewv[8];
    #pragma unroll
    for (int e = 0; e < 8; ++e) {
        float v = entity_masks[b * 8 + e] ? sc[e] : -INFINITY;
        ewv[e] = v; mx = fmaxf(mx, v);
    }
    float den = 0.f;
    #pragma unroll
    for (int e = 0; e < 8; ++e) {
        ewv[e] = entity_masks[b * 8 + e] ? expf(ewv[e] - mx) : 0.f;
        den += ewv[e];
    }
    float accp = 0.f;
    #pragma unroll
    for (int e = 0; e < 8; ++e) accp += (ewv[e] / den) * ee[e][j];
    p[j] = tanhf(accp);
    __syncthreads();

    for (int s0 = wave; s0 < 256; s0 += 4) {
        const float* row = enc + ((size_t)b * TH + spos[s0]) * 256;
        float v = 0.f;
        #pragma unroll
        for (int i = 0; i < 4; ++i) { int c = lane + 64 * i; v += row[c] * p[c]; }
        #pragma unroll
        for (int o = 32; o > 0; o >>= 1) v += __shfl_down(v, o);
        if (lane == 0) sc[s0] = v;
    }
    __syncthreads();

    float sl  = slice_lens[b];
    int   smk = slice_masks[b * 256 + j];
    float wv  = smk ? sc[j] : -INFINITY;
    float bm = wv;
    #pragma unroll
    for (int o = 32; o > 0; o >>= 1) bm = fmaxf(bm, __shfl_down(bm, o));
    __syncthreads();
    if (lane == 0) red[wave] = bm;
    __syncthreads();
    bm = fmaxf(fmaxf(red[0], red[1]), fmaxf(red[2], red[3]));
    float ex = smk ? expf(wv - bm) : 0.f;
    float sm2 = ex;
    #pragma unroll
    for (int o = 32; o > 0; o >>= 1) sm2 += __shfl_down(sm2, o);
    __syncthreads();
    if (lane == 0) red[wave] = sm2;
    __syncthreads();
    sm2 = red[0] + red[1] + red[2] + red[3];
    float ww = ex / sm2 * sl;
    float rl = (ww > 0.05f) ? (ww / sl) : 0.f;   // BETA = 0.05
    float rm = rl;
    #pragma unroll
    for (int o = 32; o > 0; o >>= 1) rm = fmaxf(rm, __shfl_down(rm, o));
    __syncthreads();
    if (lane == 0) red[wave] = rm;
    __syncthreads();
    rm = fmaxf(fmaxf(red[0], red[1]), fmaxf(red[2], red[3]));
    rl = rl / rm;
    rela[j] = rl;
    __syncthreads();

    for (int n = wave; n < 264; n += 4) {
        float v = 0.f;
        if (n < 8) {
            #pragma unroll
            for (int i = 0; i < 4; ++i) { int c = lane + 64 * i; v += tanhf(ee[n][c]) * aw[c]; }
        } else {
            int s0 = n - 8;
            const float* row = enc + ((size_t)b * TH + spos[s0]) * 256;
            float rl2 = rela[s0];
            #pragma unroll
            for (int i = 0; i < 4; ++i) { int c = lane + 64 * i; v += tanhf(rl2 * row[c]) * aw[c]; }
        }
        #pragma unroll
        for (int o = 32; o > 0; o >>= 1) v += __shfl_down(v, o);
        if (lane == 0) sc[n] = v;
    }
    __syncthreads();

    float a1 = sc[j];       a1 = (a1 == 0.f) ? -INFINITY : a1;
    float a2 = (j < 8) ? sc[256 + j] : -INFINITY;
    if (a2 == 0.f) a2 = -INFINITY;
    float am = fmaxf(a1, a2);
    #pragma unroll
    for (int o = 32; o > 0; o >>= 1) am = fmaxf(am, __shfl_down(am, o));
    __syncthreads();
    if (lane == 0) red[wave] = am;
    __syncthreads();
    am = fmaxf(fmaxf(red[0], red[1]), fmaxf(red[2], red[3]));
    float e1 = (a1 == -INFINITY) ? 0.f : expf(a1 - am);
    float e2 = (a2 == -INFINITY) ? 0.f : expf(a2 - am);
    float esum = e1 + e2;
    #pragma unroll
    for (int o = 32; o > 0; o >>= 1) esum += __shfl_down(esum, o);
    __syncthreads();
    if (lane == 0) red[wave] = esum;
    __syncthreads();
    esum = red[0] + red[1] + red[2] + red[3];
    __syncthreads();
    sc[j] = e1 / esum;
    if (j < 8) sc[256 + j] = e2 / esum;
    __syncthreads();

    float att = 0.f;
    #pragma unroll
    for (int n = 0; n < 8; ++n) att += sc[n] * ee[n][j];
    for (int s0 = 0; s0 < 256; ++s0) {
        float scn = sc[8 + s0];
        if (scn > 0.f)
            att += scn * rela[s0] * enc[((size_t)b * TH + spos[s0]) * 256 + j];
    }
    float ta = tanhf(att);

    for (int l = 0; l < 19; ++l) {
        float v = ta * dense_W[l * 256 + j];
        #pragma unroll
        for (int o = 32; o > 0; o >>= 1) v += __shfl_down(v, o);
        __syncthreads();
        if (lane == 0) red[wave] = v;
        __syncthreads();
        if (j == 0) out[b * 19 + l] = red[0] + red[1] + red[2] + red[3] + dense_b[l];
    }
}

extern "C" void kernel_launch(void* const* d_in, const int* in_sizes, int n_in,
                              void* d_out, int out_size, void* d_ws, size_t ws_size,
                              hipStream_t stream) {
    (void)in_sizes; (void)n_in; (void)out_size; (void)ws_size;
    const int*   sents        = (const int*)d_in[0];
    const int*   lens         = (const int*)d_in[1];
    const int*   entities     = (const int*)d_in[2];
    const int*   slices       = (const int*)d_in[3];
    const float* slice_lens   = (const float*)d_in[4];
    const int*   entity_masks = (const int*)d_in[5];
    const int*   slice_masks  = (const int*)d_in[6];
    const float* emb          = (const float*)d_in[7];
    const float* Q            = (const float*)d_in[8];
    const float* R            = (const float*)d_in[9];
    const float* Wih_f        = (const float*)d_in[10];
    const float* Whh_f        = (const float*)d_in[11];
    const float* bih_f        = (const float*)d_in[12];
    const float* bhh_f        = (const float*)d_in[13];
    const float* Wih_b        = (const float*)d_in[14];
    const float* Whh_b        = (const float*)d_in[15];
    const float* bih_b        = (const float*)d_in[16];
    const float* bhh_b        = (const float*)d_in[17];
    const float* ent_W        = (const float*)d_in[18];
    const float* ent_b        = (const float*)d_in[19];
    const float* att_w        = (const float*)d_in[20];
    const float* dense_W      = (const float*)d_in[21];
    const float* dense_b      = (const float*)d_in[22];

    // ws: enc [64][512][256] f32 (33.5MB) | Wh 1048576 halfs (2MB)
    float*  enc = (float*)d_ws;
    __half* Wh  = (__half*)(enc + (size_t)Bsz * TH * 256);

    const int smem_bytes = SMEMF * 4;   // 154624 B
    hipFuncSetAttribute(reinterpret_cast<const void*>(scan_k),
                        hipFuncAttributeMaxDynamicSharedMemorySize, smem_bytes);

    hipMemsetAsync(enc, 0, (size_t)Bsz * TH * 256 * sizeof(float), stream);
    pack_k<<<512, 256, 0, stream>>>(Q, R, Wih_f, Whh_f, Wih_b, Whh_b, Wh);
    scan_k<<<64, 512, smem_bytes, stream>>>(sents, lens, emb,
                                            bih_f, bhh_f, bih_b, bhh_b,
                                            Wh, enc);
    epi_k<<<64, 256, 0, stream>>>(enc, entities, slices, slice_lens,
                                  entity_masks, slice_masks, ent_W, ent_b,
                                  att_w, dense_W, dense_b, (float*)d_out);
}